// Round 8
// baseline (405.675 us; speedup 1.0000x reference)
//
#include <hip/hip_runtime.h>
#include <hip/hip_bf16.h>
#include <math.h>

#define LEAKY 0.01f
#define SCAN_BLOCK 256
#define SCAN_ITEMS 4
#define SCAN_TILE (SCAN_BLOCK * SCAN_ITEMS)  // 1024 items per block

struct __align__(8) Bf4 { __hip_bfloat16 a, b, c, d; };

__device__ __forceinline__ float bfu(unsigned short u) {
    return __uint_as_float((unsigned)u << 16);
}

__global__ void zero_i32(int* __restrict__ p, int n) {
    int i = blockIdx.x * blockDim.x + threadIdx.x;
    if (i < n) p[i] = 0;
}

// counts degree AND records each edge's rank within its row (kills fill atomic)
__global__ void count_edges(const int* __restrict__ row, int E,
                            int* __restrict__ deg, int* __restrict__ rank) {
    int i = blockIdx.x * blockDim.x + threadIdx.x;
    if (i < E) rank[i] = atomicAdd(&deg[row[i]], 1);
}

// ---- 2-phase device-wide exclusive scan of deg[N] -> row_ptr[N+1] ----
// (phase2's tiny scan of block sums is done redundantly inside phase3)
__global__ __launch_bounds__(SCAN_BLOCK) void scan_phase1(
    const int* __restrict__ deg, int* __restrict__ blocksum, int N) {
    __shared__ int red[SCAN_BLOCK];
    int b = blockIdx.x, t = threadIdx.x;
    int base = b * SCAN_TILE + t * SCAN_ITEMS;
    int s = 0;
#pragma unroll
    for (int j = 0; j < SCAN_ITEMS; j++) {
        int i = base + j;
        if (i < N) s += deg[i];
    }
    red[t] = s;
    __syncthreads();
    for (int off = SCAN_BLOCK / 2; off > 0; off >>= 1) {
        if (t < off) red[t] += red[t + off];
        __syncthreads();
    }
    if (t == 0) blocksum[b] = red[0];
}

__global__ __launch_bounds__(SCAN_BLOCK) void scan_phase3(
    const int* __restrict__ deg, const int* __restrict__ blocksum,
    int* __restrict__ row_ptr, int G, int N) {
    __shared__ int bs[SCAN_BLOCK];
    __shared__ int red[SCAN_BLOCK];
    int b = blockIdx.x, t = threadIdx.x;
    // redundant per-block scan of the <=256 block sums (saves a dispatch)
    bs[t] = (t < G) ? blocksum[t] : 0;
    __syncthreads();
    for (int off = 1; off < SCAN_BLOCK; off <<= 1) {
        int v = (t >= off) ? bs[t - off] : 0;
        __syncthreads();
        bs[t] += v;
        __syncthreads();
    }
    int boff = (b == 0) ? 0 : bs[b - 1];
    if (b == 0 && t == 0) row_ptr[N] = bs[G - 1];

    int base = b * SCAN_TILE + t * SCAN_ITEMS;
    int v[SCAN_ITEMS];
    int s = 0;
#pragma unroll
    for (int j = 0; j < SCAN_ITEMS; j++) {
        int i = base + j;
        v[j] = (i < N) ? deg[i] : 0;
        s += v[j];
    }
    red[t] = s;
    __syncthreads();
    for (int off = 1; off < SCAN_BLOCK; off <<= 1) {
        int x = (t >= off) ? red[t - off] : 0;
        __syncthreads();
        red[t] += x;
        __syncthreads();
    }
    int run = boff + ((t == 0) ? 0 : red[t - 1]);
#pragma unroll
    for (int j = 0; j < SCAN_ITEMS; j++) {
        int i = base + j;
        if (i < N) { row_ptr[i] = run; run += v[j]; }
    }
}
// ----------------------------------------------------------------------

// a0 = concat(user_embed, entity_embed) (fp32) + bf16 gather copy
__global__ void build_a0(const float4* __restrict__ ue, const float4* __restrict__ ee,
                         float4* __restrict__ a0, __hip_bfloat16* __restrict__ a0b,
                         int nu4, int ntot4) {
    int i = blockIdx.x * blockDim.x + threadIdx.x;
    if (i < ntot4) {
        float4 v = (i < nu4) ? ue[i] : ee[i - nu4];
        a0[i] = v;
        Bf4 q = {__float2bfloat16(v.x), __float2bfloat16(v.y),
                 __float2bfloat16(v.z), __float2bfloat16(v.w)};
        *(Bf4*)&a0b[(size_t)i * 4] = q;
    }
}

// atomic-free CSR fill using precomputed ranks
__global__ void fill_csr(const int* __restrict__ row, const int* __restrict__ col,
                         const float* __restrict__ val, const int* __restrict__ rank,
                         const int* __restrict__ row_ptr, int E,
                         int2* __restrict__ csr) {
    int i = blockIdx.x * blockDim.x + threadIdx.x;
    if (i < E) {
        int p = row_ptr[row[i]] + rank[i];
        csr[p] = make_int2(col[i], __float_as_int(val[i]));
    }
}

__device__ __forceinline__ void fma4(float o[4], float sv, const float4& wv) {
    o[0] = fmaf(sv, wv.x, o[0]);
    o[1] = fmaf(sv, wv.y, o[1]);
    o[2] = fmaf(sv, wv.z, o[2]);
    o[3] = fmaf(sv, wv.w, o[3]);
}

// Fused GNN layer. Block = 256 thr (4 waves), 8 nodes per wave.
// Phase 1 (vectorized gather): lane = (g = lane>>4 edge-subgroup, j = lane&15
//   dim-quarter). Coalesced 64-edge metadata load -> per 4-edge sub-chunk:
//   2 bpermute (col/val) + ONE ushort4 gather (8 B/lane, 16 lanes per
//   neighbor row, 4 edges per VMEM instr) + 4 cvt + 4 fma. End of node:
//   shfl_xor(16,32) folds the 4 edge-groups; group 0 writes S as float4s.
// Phase 2: register-blocked MLP, weights from global (L1/L2-resident), LDS
//   holds only S rows (stride 132, conflict-free).
template<int DOUT>
__global__ __launch_bounds__(256, 4) void gnn_layer(
    const float* __restrict__ feats, const __hip_bfloat16* __restrict__ featsb,
    const int2* __restrict__ csr, const int* __restrict__ row_ptr,
    const float* __restrict__ W1, const float* __restrict__ b1,
    const float* __restrict__ W2, const float* __restrict__ b2,
    float* __restrict__ out, __hip_bfloat16* __restrict__ outb, int N) {
    __shared__ __align__(16) float S[32 * 132];
    int wv = threadIdx.x >> 6, lane = threadIdx.x & 63;
    int g = lane >> 4, j = lane & 15;
    const ushort* fb = (const ushort*)featsb;
    int nb = blockIdx.x * 32 + wv * 8;  // first node of this wave

    // ---- phase 1: aggregate 8 nodes ----
    for (int ni = 0; ni < 8; ni++) {
        int node = nb + ni;
        if (node >= N) break;
        int e0 = row_ptr[node];
        int degn = row_ptr[node + 1] - e0;
        float a0_ = 0.f, a1_ = 0.f, a2_ = 0.f, a3_ = 0.f;
        int done = 0;
        while (done < degn) {
            int take = min(64, degn - done);
            int2 m = make_int2(0, 0);
            if (lane < take) m = csr[e0 + done + lane];
            int nsub = (take + 3) >> 2;
            int c = 0;
            for (; c + 4 <= nsub; c += 4) {
                int s0 = c * 4 + g;
                int c0 = __shfl(m.x, s0, 64);      float v0 = __int_as_float(__shfl(m.y, s0, 64));
                int c1 = __shfl(m.x, s0 + 4, 64);  float v1 = __int_as_float(__shfl(m.y, s0 + 4, 64));
                int c2 = __shfl(m.x, s0 + 8, 64);  float v2 = __int_as_float(__shfl(m.y, s0 + 8, 64));
                int c3 = __shfl(m.x, s0 + 12, 64); float v3 = __int_as_float(__shfl(m.y, s0 + 12, 64));
                ushort4 q0 = *(const ushort4*)&fb[(size_t)c0 * 64 + j * 4];
                ushort4 q1 = *(const ushort4*)&fb[(size_t)c1 * 64 + j * 4];
                ushort4 q2 = *(const ushort4*)&fb[(size_t)c2 * 64 + j * 4];
                ushort4 q3 = *(const ushort4*)&fb[(size_t)c3 * 64 + j * 4];
                a0_ = fmaf(v0, bfu(q0.x), a0_); a1_ = fmaf(v0, bfu(q0.y), a1_);
                a2_ = fmaf(v0, bfu(q0.z), a2_); a3_ = fmaf(v0, bfu(q0.w), a3_);
                a0_ = fmaf(v1, bfu(q1.x), a0_); a1_ = fmaf(v1, bfu(q1.y), a1_);
                a2_ = fmaf(v1, bfu(q1.z), a2_); a3_ = fmaf(v1, bfu(q1.w), a3_);
                a0_ = fmaf(v2, bfu(q2.x), a0_); a1_ = fmaf(v2, bfu(q2.y), a1_);
                a2_ = fmaf(v2, bfu(q2.z), a2_); a3_ = fmaf(v2, bfu(q2.w), a3_);
                a0_ = fmaf(v3, bfu(q3.x), a0_); a1_ = fmaf(v3, bfu(q3.y), a1_);
                a2_ = fmaf(v3, bfu(q3.z), a2_); a3_ = fmaf(v3, bfu(q3.w), a3_);
            }
            for (; c < nsub; c++) {
                int s0 = c * 4 + g;
                int c0 = __shfl(m.x, s0, 64);
                float v0 = __int_as_float(__shfl(m.y, s0, 64));
                ushort4 q0 = *(const ushort4*)&fb[(size_t)c0 * 64 + j * 4];
                a0_ = fmaf(v0, bfu(q0.x), a0_); a1_ = fmaf(v0, bfu(q0.y), a1_);
                a2_ = fmaf(v0, bfu(q0.z), a2_); a3_ = fmaf(v0, bfu(q0.w), a3_);
            }
            done += take;
        }
        // fold the 4 edge-groups (all lanes end with the full sum)
        a0_ += __shfl_xor(a0_, 16, 64); a0_ += __shfl_xor(a0_, 32, 64);
        a1_ += __shfl_xor(a1_, 16, 64); a1_ += __shfl_xor(a1_, 32, 64);
        a2_ += __shfl_xor(a2_, 16, 64); a2_ += __shfl_xor(a2_, 32, 64);
        a3_ += __shfl_xor(a3_, 16, 64); a3_ += __shfl_xor(a3_, 32, 64);
        if (g == 0) {
            float4 xv = *(const float4*)&feats[(size_t)node * 64 + j * 4];
            float* sp = &S[(wv * 8 + ni) * 132];
            float4 s1v = {xv.x + a0_, xv.y + a1_, xv.z + a2_, xv.w + a3_};
            float4 s2v = {xv.x * a0_, xv.y * a1_, xv.z * a2_, xv.w * a3_};
            *(float4*)&sp[j * 4]      = s1v;
            *(float4*)&sp[64 + j * 4] = s2v;
        }
    }
    __threadfence_block();  // wave-local LDS write -> cross-lane read ordering

    // ---- phase 2: MLP + epilogue ----
    if constexpr (DOUT == 64) {
        int strip = lane & 15, gg = lane >> 4;   // 16 strips x 4 dims; 4 node-pairs
        int d0 = strip * 4;
        float4 b1v = *(const float4*)&b1[d0];
        float4 b2v = *(const float4*)&b2[d0];
        float oa[4] = {b1v.x + b2v.x, b1v.y + b2v.y, b1v.z + b2v.z, b1v.w + b2v.w};
        float ob[4] = {oa[0], oa[1], oa[2], oa[3]};
        const float* spa = &S[(wv * 8 + 2 * gg) * 132];
        const float* spb = spa + 132;
#pragma unroll
        for (int half = 0; half < 2; half++) {
            const float* W  = half ? W2 : W1;
            const float* sa = spa + half * 64;
            const float* sb = spb + half * 64;
#pragma unroll 2
            for (int k = 0; k < 64; k += 4) {
                float4 va = *(const float4*)&sa[k];
                float4 vb = *(const float4*)&sb[k];
                float4 wr0 = *(const float4*)&W[(k + 0) * 64 + d0];
                float4 wr1 = *(const float4*)&W[(k + 1) * 64 + d0];
                float4 wr2 = *(const float4*)&W[(k + 2) * 64 + d0];
                float4 wr3 = *(const float4*)&W[(k + 3) * 64 + d0];
                fma4(oa, va.x, wr0); fma4(oa, va.y, wr1);
                fma4(oa, va.z, wr2); fma4(oa, va.w, wr3);
                fma4(ob, vb.x, wr0); fma4(ob, vb.y, wr1);
                fma4(ob, vb.z, wr2); fma4(ob, vb.w, wr3);
            }
        }
#pragma unroll
        for (int t = 0; t < 2; t++) {
            float* o = t ? ob : oa;
            float h0 = (o[0] > 0.f) ? o[0] : LEAKY * o[0];
            float h1 = (o[1] > 0.f) ? o[1] : LEAKY * o[1];
            float h2 = (o[2] > 0.f) ? o[2] : LEAKY * o[2];
            float h3 = (o[3] > 0.f) ? o[3] : LEAKY * o[3];
            float ss = h0 * h0 + h1 * h1 + h2 * h2 + h3 * h3;
            ss += __shfl_xor(ss, 1, 64);
            ss += __shfl_xor(ss, 2, 64);
            ss += __shfl_xor(ss, 4, 64);
            ss += __shfl_xor(ss, 8, 64);   // 16 lanes = one node
            float sc = 1.0f / fmaxf(sqrtf(ss), 1e-12f);
            int node = nb + 2 * gg + t;
            if (node < N) {
                float4 r = {h0 * sc, h1 * sc, h2 * sc, h3 * sc};
                *(float4*)&out[(size_t)node * 64 + d0] = r;
                Bf4 q = {__float2bfloat16(r.x), __float2bfloat16(r.y),
                         __float2bfloat16(r.z), __float2bfloat16(r.w)};
                *(Bf4*)&outb[(size_t)node * 64 + d0] = q;
            }
        }
    } else {
        int strip = lane & 7, nI = lane >> 3;    // 8 strips x 4 dims; 8 nodes
        int d0 = strip * 4;
        float4 b1v = *(const float4*)&b1[d0];
        float4 b2v = *(const float4*)&b2[d0];
        float o[4] = {b1v.x + b2v.x, b1v.y + b2v.y, b1v.z + b2v.z, b1v.w + b2v.w};
        const float* sp = &S[(wv * 8 + nI) * 132];
#pragma unroll
        for (int half = 0; half < 2; half++) {
            const float* W  = half ? W2 : W1;
            const float* sv = sp + half * 64;
#pragma unroll 2
            for (int k = 0; k < 64; k += 4) {
                float4 v   = *(const float4*)&sv[k];
                float4 wr0 = *(const float4*)&W[(k + 0) * 32 + d0];
                float4 wr1 = *(const float4*)&W[(k + 1) * 32 + d0];
                float4 wr2 = *(const float4*)&W[(k + 2) * 32 + d0];
                float4 wr3 = *(const float4*)&W[(k + 3) * 32 + d0];
                fma4(o, v.x, wr0); fma4(o, v.y, wr1);
                fma4(o, v.z, wr2); fma4(o, v.w, wr3);
            }
        }
        float h0 = (o[0] > 0.f) ? o[0] : LEAKY * o[0];
        float h1 = (o[1] > 0.f) ? o[1] : LEAKY * o[1];
        float h2 = (o[2] > 0.f) ? o[2] : LEAKY * o[2];
        float h3 = (o[3] > 0.f) ? o[3] : LEAKY * o[3];
        float ss = h0 * h0 + h1 * h1 + h2 * h2 + h3 * h3;
        ss += __shfl_xor(ss, 1, 64);
        ss += __shfl_xor(ss, 2, 64);
        ss += __shfl_xor(ss, 4, 64);       // 8 lanes = one node
        float sc = 1.0f / fmaxf(sqrtf(ss), 1e-12f);
        int node = nb + nI;
        if (node < N) {
            float4 r = {h0 * sc, h1 * sc, h2 * sc, h3 * sc};
            *(float4*)&out[(size_t)node * 32 + d0] = r;
        }
    }
}

// final = concat(a0, a1, a2); score[b] = dot(final[u], final[NU+i]) over 160 dims
__global__ __launch_bounds__(256) void score_pairs(
    const float* __restrict__ a0, const float* __restrict__ a1,
    const float* __restrict__ a2,
    const int* __restrict__ uid, const int* __restrict__ iid,
    float* __restrict__ out, int B, int NU) {
    int wave = threadIdx.x >> 6, lane = threadIdx.x & 63;
    int p = blockIdx.x * 4 + wave;
    if (p >= B) return;
    int u = uid[p], it = iid[p];
    size_t un = (size_t)u, in = (size_t)(NU + it);
    float s = a0[un * 64 + lane] * a0[in * 64 + lane];
    s = fmaf(a1[un * 64 + lane], a1[in * 64 + lane], s);
    if (lane < 32) s = fmaf(a2[un * 32 + lane], a2[in * 32 + lane], s);
#pragma unroll
    for (int m = 32; m >= 1; m >>= 1) s += __shfl_xor(s, m, 64);
    if (lane == 0) out[p] = s;
}

extern "C" void kernel_launch(void* const* d_in, const int* in_sizes, int n_in,
                              void* d_out, int out_size, void* d_ws, size_t ws_size,
                              hipStream_t stream) {
    const int*   edge_row  = (const int*)d_in[0];
    const int*   edge_col  = (const int*)d_in[1];
    const float* edge_vals = (const float*)d_in[2];
    const float* ue        = (const float*)d_in[3];
    const float* ee        = (const float*)d_in[4];
    const float* W1_0 = (const float*)d_in[5];
    const float* b1_0 = (const float*)d_in[6];
    const float* W2_0 = (const float*)d_in[7];
    const float* b2_0 = (const float*)d_in[8];
    const float* W1_1 = (const float*)d_in[9];
    const float* b1_1 = (const float*)d_in[10];
    const float* W2_1 = (const float*)d_in[11];
    const float* b2_1 = (const float*)d_in[12];
    const int*   uid  = (const int*)d_in[13];
    const int*   iid  = (const int*)d_in[14];
    float* out = (float*)d_out;

    const int E  = in_sizes[0];
    const int NU = in_sizes[3] / 64;
    const int NE = in_sizes[4] / 64;
    const int N  = NU + NE;
    const int B  = in_sizes[13];
    const int G  = (N + SCAN_TILE - 1) / SCAN_TILE;  // must be <= SCAN_BLOCK

    char* ws = (char*)d_ws;
    size_t off = 0;
    auto alloc = [&](size_t bytes) -> char* {
        char* p = ws + off;
        off = (off + bytes + 255) & ~(size_t)255;
        return p;
    };
    int*   deg      = (int*)alloc((size_t)N * 4);
    int*   rank     = (int*)alloc((size_t)E * 4);
    int*   row_ptr  = (int*)alloc((size_t)(N + 1) * 4);
    int*   blocksum = (int*)alloc((size_t)1024 * 4);
    int2*  csr      = (int2*)alloc((size_t)E * 8);
    float* a0       = (float*)alloc((size_t)N * 64 * 4);
    float* a1       = (float*)alloc((size_t)N * 64 * 4);
    float* a2       = (float*)alloc((size_t)N * 32 * 4);
    __hip_bfloat16* a0b = (__hip_bfloat16*)alloc((size_t)N * 64 * 2);
    __hip_bfloat16* a1b = (__hip_bfloat16*)alloc((size_t)N * 64 * 2);
    (void)ws_size; (void)n_in; (void)out_size; (void)NE;

    zero_i32<<<(N + 255) / 256, 256, 0, stream>>>(deg, N);
    count_edges<<<(E + 255) / 256, 256, 0, stream>>>(edge_row, E, deg, rank);
    scan_phase1<<<G, SCAN_BLOCK, 0, stream>>>(deg, blocksum, N);
    scan_phase3<<<G, SCAN_BLOCK, 0, stream>>>(deg, blocksum, row_ptr, G, N);
    fill_csr<<<(E + 255) / 256, 256, 0, stream>>>(edge_row, edge_col, edge_vals,
                                                  rank, row_ptr, E, csr);
    int ntot4 = N * 16, nu4 = NU * 16;
    build_a0<<<(ntot4 + 255) / 256, 256, 0, stream>>>((const float4*)ue, (const float4*)ee,
                                                      (float4*)a0, a0b, nu4, ntot4);
    gnn_layer<64><<<(N + 31) / 32, 256, 0, stream>>>(a0, a0b, csr, row_ptr,
                                                     W1_0, b1_0, W2_0, b2_0, a1, a1b, N);
    gnn_layer<32><<<(N + 31) / 32, 256, 0, stream>>>(a1, a1b, csr, row_ptr,
                                                     W1_1, b1_1, W2_1, b2_1, a2, nullptr, N);
    score_pairs<<<(B + 3) / 4, 256, 0, stream>>>(a0, a1, a2, uid, iid, out, B, NU);
}